// Round 9
// baseline (306.168 us; speedup 1.0000x reference)
//
#include <hip/hip_runtime.h>
#include <math.h>
#include <stdint.h>

#define BROWS 4096
#define VCOLS 50257
#define KTOP  64
#define CAP   2048      // per-row LDS candidate buffer (floats) = 8KB
#define CHECK_AT 1024   // compact when cnt may overflow next 1024-elem tile
#define NREG 32         // CAP / 64 lanes

// Order-preserving float->uint key (monotone total order, handles negatives/inf)
__device__ __forceinline__ unsigned f2key(float f) {
    unsigned u = __float_as_uint(f);
    return u ^ ((unsigned)((int)u >> 31) | 0x80000000u);
}
__device__ __forceinline__ float key2f(unsigned k) {
    unsigned u = (k & 0x80000000u) ? (k ^ 0x80000000u) : ~k;
    return __uint_as_float(u);
}

__device__ __forceinline__ int wave_sum_i(int c) {
    #pragma unroll
    for (int d = 1; d < 64; d <<= 1) c += __shfl_xor(c, d);
    return c;
}

// Read CAP floats from LDS as keys into 32 regs/lane; slots >= cnt -> key 0.
__device__ __forceinline__ void load_keys(const float* s_buf, unsigned cnt, int lane, unsigned* key) {
    #pragma unroll
    for (int j = 0; j < NREG / 4; ++j) {
        const float4 v = ((const float4*)s_buf)[j * 64 + lane];
        const int base = (j * 64 + lane) * 4;
        key[4*j+0] = (base + 0 < (int)cnt) ? f2key(v.x) : 0u;
        key[4*j+1] = (base + 1 < (int)cnt) ? f2key(v.y) : 0u;
        key[4*j+2] = (base + 2 < (int)cnt) ? f2key(v.z) : 0u;
        key[4*j+3] = (base + 3 < (int)cnt) ? f2key(v.w) : 0u;
    }
}

// Wave-local compaction (INLINE, by-ref — no ABI clobber; rare after seeding).
// Keeps elements >= approx 64th-largest-so-far; count(buf >= thr) >= 64 after.
__device__ __forceinline__ void wave_compact(float* s_buf, unsigned& cnt, float& thr, int lane) {
    __builtin_amdgcn_wave_barrier();
    unsigned key[NREG];
    load_keys(s_buf, cnt, lane, key);
    unsigned kmx = 0u;
    #pragma unroll
    for (int j = 0; j < NREG; ++j) kmx = max(kmx, key[j]);
    #pragma unroll
    for (int d = 1; d < 64; d <<= 1) kmx = max(kmx, (unsigned)__shfl_xor((int)kmx, d));

    unsigned lo = f2key(thr);   // invariant: count(key >= lo) >= 64
    unsigned hi = kmx + 1u;
    for (int it = 0; it < 12; ++it) {
        if (hi - lo <= 1u) break;
        const unsigned mid = lo + ((hi - lo) >> 1);
        int c = 0;
        #pragma unroll
        for (int j = 0; j < NREG; ++j) c += (key[j] >= mid) ? 1 : 0;
        c = wave_sum_i(c);
        if (c >= KTOP) lo = mid; else hi = mid;
    }
    int cl = 0; unsigned sm = 0u;
    #pragma unroll
    for (int j = 0; j < NREG; ++j) { const bool s = key[j] >= lo; sm |= (unsigned)s << j; cl += s ? 1 : 0; }
    int incl = cl;
    #pragma unroll
    for (int d = 1; d < 64; d <<= 1) { const int t = __shfl_up(incl, d); if (lane >= d) incl += t; }
    int pos = incl - cl;
    __builtin_amdgcn_wave_barrier();
    #pragma unroll
    for (int j = 0; j < NREG; ++j) if ((sm >> j) & 1u) s_buf[pos++] = key2f(key[j]);
    cnt = (unsigned)__shfl(incl, 63);
    thr = key2f(lo);
    __builtin_amdgcn_wave_barrier();
}

// Exact top-64 + label-smoothed CE over {truth, top64}. Tie-correct via
// boundary multiplicity. Runs once per row, after streaming.
__device__ __forceinline__ float wave_final(const float* s_buf, unsigned cnt, float thr, float tv, int lane) {
    __builtin_amdgcn_wave_barrier();
    unsigned key[NREG];
    load_keys(s_buf, cnt, lane, key);
    unsigned kmx = 0u;
    #pragma unroll
    for (int j = 0; j < NREG; ++j) kmx = max(kmx, key[j]);
    #pragma unroll
    for (int d = 1; d < 64; d <<= 1) kmx = max(kmx, (unsigned)__shfl_xor((int)kmx, d));

    unsigned lo = f2key(thr);
    unsigned hi = kmx + 1u;
    while (hi - lo > 1u) {
        const unsigned mid = lo + ((hi - lo) >> 1);
        int c = 0;
        #pragma unroll
        for (int j = 0; j < NREG; ++j) c += (key[j] >= mid) ? 1 : 0;
        c = wave_sum_i(c);
        if (c >= KTOP) lo = mid; else hi = mid;
    }
    const float vmax = key2f(kmx);
    const float m = fmaxf(vmax, tv);
    float se = 0.f, sv = 0.f; int cg = 0;
    #pragma unroll
    for (int j = 0; j < NREG; ++j) {
        if (key[j] > lo) { const float v = key2f(key[j]); se += __expf(v - m); sv += v; ++cg; }
    }
    #pragma unroll
    for (int d = 1; d < 64; d <<= 1) {
        se += __shfl_xor(se, d); sv += __shfl_xor(sv, d); cg += __shfl_xor(cg, d);
    }
    const float v64 = key2f(lo);            // exact 64th largest
    const int nb = KTOP - cg;               // boundary multiplicity (>=1)
    se += (float)nb * __expf(v64 - m);
    sv += (float)nb * v64;
    se += __expf(tv - m);
    const float lse = m + __logf(se);
    return lse - 0.9f * tv - 0.1f * ((sv + tv) * (1.0f / 65.0f));
}

// Ballot-aggregated wave insert; cnt is a wave-uniform register (no atomics).
__device__ __forceinline__ void ins1(float v, int gi, int tgt, float thr,
                                     float* s_buf, unsigned& cnt, unsigned long long lt) {
    const bool p = (v > thr) && (gi != tgt);
    const unsigned long long mk = __ballot(p ? 1 : 0);
    if (mk) {
        if (p) {
            const unsigned pos = cnt + (unsigned)__popcll(mk & lt);
            if (pos < CAP) s_buf[pos] = v;
        }
        cnt += (unsigned)__popcll(mk);
    }
}
__device__ __forceinline__ void ins4(const float4 q, int gb, int tgt, float thr,
                                     float* s_buf, unsigned& cnt, unsigned long long lt) {
    ins1(q.x, gb + 0, tgt, thr, s_buf, cnt, lt);
    ins1(q.y, gb + 1, tgt, thr, s_buf, cnt, lt);
    ins1(q.z, gb + 2, tgt, thr, s_buf, cnt, lt);
    ins1(q.w, gb + 3, tgt, thr, s_buf, cnt, lt);
}

#define LOADT(A0,A1,A2,A3, tq) do { const int b_ = (tq)*256 + lane; \
    A0 = vp[b_]; A1 = vp[b_+64]; A2 = vp[b_+128]; A3 = vp[b_+192]; } while (0)

#define PROC(A0,A1,A2,A3, tq) do { \
    const int bq_ = (tq)*256 + lane; \
    const float mA_ = fmaxf(fmaxf(A0.x,A0.y), fmaxf(A0.z,A0.w)); \
    const float mB_ = fmaxf(fmaxf(A1.x,A1.y), fmaxf(A1.z,A1.w)); \
    const float mC_ = fmaxf(fmaxf(A2.x,A2.y), fmaxf(A2.z,A2.w)); \
    const float mD_ = fmaxf(fmaxf(A3.x,A3.y), fmaxf(A3.z,A3.w)); \
    const float m16_ = fmaxf(fmaxf(mA_,mB_), fmaxf(mC_,mD_)); \
    if (__ballot((m16_ > thr) ? 1 : 0)) { \
        ins4(A0, pad + 4*bq_,       tgt, thr, s_buf, cnt, lt); \
        ins4(A1, pad + 4*(bq_+64),  tgt, thr, s_buf, cnt, lt); \
        ins4(A2, pad + 4*(bq_+128), tgt, thr, s_buf, cnt, lt); \
        ins4(A3, pad + 4*(bq_+192), tgt, thr, s_buf, cnt, lt); \
    } \
    if (cnt > CHECK_AT) wave_compact(s_buf, cnt, thr, lane); \
} while (0)

// One wave (64-thread block) per row. Threshold seeded from tile 0 (kills
// warmup inserts + nearly all mid-row compacts); depth-2 register prefetch
// (no calls in the hot loop -> no ABI spill); fused last-block reduction.
__global__ __launch_bounds__(64) void topk_ce_kernel(
        const float* __restrict__ input, const int* __restrict__ target,
        float* __restrict__ per_ex, unsigned* __restrict__ counter,
        float* __restrict__ out) {
    __shared__ float s_buf[CAP];
    const int row  = blockIdx.x;
    const int lane = threadIdx.x;
    const float* __restrict__ rowp = input + (size_t)row * (size_t)VCOLS;
    const int tgt = target[row];
    const float tv = rowp[tgt];               // independent load, issued early
    const unsigned long long lt = (1ull << lane) - 1ull;

    unsigned cnt = 0u;
    float thr;

    // Rows are only 4B-aligned (V % 4 == 1).
    const int pad   = (int)((4u - ((((uintptr_t)rowp) >> 2) & 3u)) & 3u);
    const int nvec  = (VCOLS - pad) >> 2;
    const int ntail = (VCOLS - pad) & 3;
    const float4* __restrict__ vp = (const float4*)(rowp + pad);
    const int ntf = nvec >> 8;   // full tiles: 256 quads = 1024 elems (= 49)

    // ---- seed thr from tile 0: bisect ~64th largest, pack >= lo (ties kept,
    //      so count(buf >= thr) >= 64 invariant holds from the start) ----
    {
        const int b = lane;
        const float4 w0 = vp[b];
        const float4 w1 = vp[b + 64];
        const float4 w2 = vp[b + 128];
        const float4 w3 = vp[b + 192];
        unsigned k[16];
        const int e0 = pad + 4 * b, e1 = pad + 4 * (b + 64),
                  e2 = pad + 4 * (b + 128), e3 = pad + 4 * (b + 192);
        k[0]  = (e0+0 != tgt) ? f2key(w0.x) : 0u;
        k[1]  = (e0+1 != tgt) ? f2key(w0.y) : 0u;
        k[2]  = (e0+2 != tgt) ? f2key(w0.z) : 0u;
        k[3]  = (e0+3 != tgt) ? f2key(w0.w) : 0u;
        k[4]  = (e1+0 != tgt) ? f2key(w1.x) : 0u;
        k[5]  = (e1+1 != tgt) ? f2key(w1.y) : 0u;
        k[6]  = (e1+2 != tgt) ? f2key(w1.z) : 0u;
        k[7]  = (e1+3 != tgt) ? f2key(w1.w) : 0u;
        k[8]  = (e2+0 != tgt) ? f2key(w2.x) : 0u;
        k[9]  = (e2+1 != tgt) ? f2key(w2.y) : 0u;
        k[10] = (e2+2 != tgt) ? f2key(w2.z) : 0u;
        k[11] = (e2+3 != tgt) ? f2key(w2.w) : 0u;
        k[12] = (e3+0 != tgt) ? f2key(w3.x) : 0u;
        k[13] = (e3+1 != tgt) ? f2key(w3.y) : 0u;
        k[14] = (e3+2 != tgt) ? f2key(w3.z) : 0u;
        k[15] = (e3+3 != tgt) ? f2key(w3.w) : 0u;
        unsigned kmx = 0u;
        #pragma unroll
        for (int j = 0; j < 16; ++j) kmx = max(kmx, k[j]);
        #pragma unroll
        for (int d = 1; d < 64; d <<= 1) kmx = max(kmx, (unsigned)__shfl_xor((int)kmx, d));
        unsigned lo = 0u, hi = kmx + 1u;
        for (int it = 0; it < 12; ++it) {
            if (hi - lo <= 1u) break;
            const unsigned mid = lo + ((hi - lo) >> 1);
            int c = 0;
            #pragma unroll
            for (int j = 0; j < 16; ++j) c += (k[j] >= mid) ? 1 : 0;
            c = wave_sum_i(c);
            if (c >= KTOP) lo = mid; else hi = mid;
        }
        int cl = 0; unsigned sm = 0u;
        #pragma unroll
        for (int j = 0; j < 16; ++j) { const bool s = k[j] >= lo; sm |= (unsigned)s << j; cl += s ? 1 : 0; }
        int incl = cl;
        #pragma unroll
        for (int d = 1; d < 64; d <<= 1) { const int t = __shfl_up(incl, d); if (lane >= d) incl += t; }
        int pos = incl - cl;
        #pragma unroll
        for (int j = 0; j < 16; ++j) if ((sm >> j) & 1u) s_buf[pos++] = key2f(k[j]);
        cnt = (unsigned)__shfl(incl, 63);   // >= 64 by construction
        thr = key2f(lo);
    }

    // <=3 prologue elements (before the 16B boundary), strict insert
    {
        const float v = (lane < pad) ? rowp[lane] : 0.f;
        const bool p = (lane < pad) && (v > thr) && (lane != tgt);
        const unsigned long long mk = __ballot(p ? 1 : 0);
        if (p) {
            const unsigned pos = cnt + (unsigned)__popcll(mk & lt);
            if (pos < CAP) s_buf[pos] = v;
        }
        cnt += (unsigned)__popcll(mk);
    }

    // full tiles 1..ntf-1, unroll-2 with register prefetch (no calls inside)
    float4 a0, a1, a2, a3, b0, b1, b2, b3;
    int t = 1;
    if (t < ntf) LOADT(a0, a1, a2, a3, t);
    for (; t + 2 <= ntf; t += 2) {
        LOADT(b0, b1, b2, b3, t + 1);
        PROC(a0, a1, a2, a3, t);
        if (t + 2 < ntf) LOADT(a0, a1, a2, a3, t + 2);
        PROC(b0, b1, b2, b3, t + 1);
    }
    if (t < ntf) PROC(a0, a1, a2, a3, t);

    // masked remainder quads (< 256), uniform trip count
    for (int k0 = ntf << 8; k0 < nvec; k0 += 64) {
        const int idx = k0 + lane;
        float4 a;
        if (idx < nvec) a = vp[idx];
        else { a.x = a.y = a.z = a.w = -INFINITY; }
        const float mA = fmaxf(fmaxf(a.x, a.y), fmaxf(a.z, a.w));
        if (__ballot((mA > thr) ? 1 : 0)) ins4(a, pad + 4 * idx, tgt, thr, s_buf, cnt, lt);
        if (cnt > CHECK_AT) wave_compact(s_buf, cnt, thr, lane);
    }

    // scalar tail (<= 3 elems)
    {
        const int idx = pad + 4 * nvec + lane;
        const float v = (lane < ntail) ? rowp[idx] : 0.f;
        const bool p = (lane < ntail) && (v > thr) && (idx != tgt);
        const unsigned long long mk = __ballot(p ? 1 : 0);
        if (p) {
            const unsigned pos = cnt + (unsigned)__popcll(mk & lt);
            if (pos < CAP) s_buf[pos] = v;
        }
        cnt += (unsigned)__popcll(mk);
    }

    const float pe = wave_final(s_buf, cnt, thr, tv, lane);

    if (per_ex) {
        unsigned done = 0u;
        if (lane == 0) {
            per_ex[row] = pe;
            __threadfence();                       // release
            done = atomicAdd(counter, 1u);         // device-scope
        }
        done = (unsigned)__shfl((int)done, 0);
        if (done == (unsigned)(BROWS - 1)) {       // last block reduces
            __threadfence();                       // acquire
            const float4* p4 = (const float4*)per_ex;
            float acc = 0.0f;
            #pragma unroll
            for (int i = 0; i < 16; ++i) {         // 16 x 64 float4 = 4096 floats
                const float4 q = p4[i * 64 + lane];
                acc += (q.x + q.y) + (q.z + q.w);
            }
            #pragma unroll
            for (int d = 1; d < 64; d <<= 1) acc += __shfl_xor(acc, d);
            if (lane == 0) out[0] = acc * (1.0f / BROWS);
        }
    } else {
        if (lane == 0) atomicAdd(out, pe * (1.0f / BROWS));
    }
}

extern "C" void kernel_launch(void* const* d_in, const int* in_sizes, int n_in,
                              void* d_out, int out_size, void* d_ws, size_t ws_size,
                              hipStream_t stream) {
    const float* input  = (const float*)d_in[0];
    const int*   target = (const int*)d_in[1];   // jax int64 -> int32 on device (x64 off)
    float* out = (float*)d_out;

    float*    per_ex  = (float*)d_ws;
    unsigned* counter = (unsigned*)((char*)d_ws + BROWS * sizeof(float));
    const size_t need = BROWS * sizeof(float) + sizeof(unsigned);

    if (ws_size >= need) {
        hipMemsetAsync(counter, 0, sizeof(unsigned), stream);   // reset done-count
        topk_ce_kernel<<<BROWS, 64, 0, stream>>>(input, target, per_ex, counter, out);
    } else {
        hipMemsetAsync(d_out, 0, sizeof(float), stream);
        topk_ce_kernel<<<BROWS, 64, 0, stream>>>(input, target, nullptr, nullptr, out);
    }
}

// Round 13
// 217.775 us; speedup vs baseline: 1.4059x; 1.4059x over previous
//
#include <hip/hip_runtime.h>
#include <math.h>
#include <stdint.h>

#define BROWS 4096
#define VCOLS 50257
#define KTOP  64
#define CAP   2048      // per-row LDS candidate buffer (floats) = 8KB
#define CHECK_AT 1024   // compact when cnt may overflow next 1024-elem tile
#define NREG 32         // CAP / 64 lanes

// Order-preserving float->uint key (monotone total order, handles negatives/inf)
__device__ __forceinline__ unsigned f2key(float f) {
    unsigned u = __float_as_uint(f);
    return u ^ ((unsigned)((int)u >> 31) | 0x80000000u);
}
__device__ __forceinline__ float key2f(unsigned k) {
    unsigned u = (k & 0x80000000u) ? (k ^ 0x80000000u) : ~k;
    return __uint_as_float(u);
}

__device__ __forceinline__ int wave_sum_i(int c) {
    #pragma unroll
    for (int d = 1; d < 64; d <<= 1) c += __shfl_xor(c, d);
    return c;
}

// Read CAP floats from LDS as keys into 32 regs/lane; slots >= cnt -> key 0.
// Lane-consecutive 16B chunks -> bank-conflict-free.
__device__ __forceinline__ void load_keys(const float* s_buf, unsigned cnt, int lane, unsigned* key) {
    #pragma unroll
    for (int j = 0; j < NREG / 4; ++j) {
        const float4 v = ((const float4*)s_buf)[j * 64 + lane];
        const int base = (j * 64 + lane) * 4;
        key[4*j+0] = (base + 0 < (int)cnt) ? f2key(v.x) : 0u;
        key[4*j+1] = (base + 1 < (int)cnt) ? f2key(v.y) : 0u;
        key[4*j+2] = (base + 2 < (int)cnt) ? f2key(v.z) : 0u;
        key[4*j+3] = (base + 3 < (int)cnt) ? f2key(v.w) : 0u;
    }
}

// Wave-local compaction (INLINE — no call ABI clobber). Keeps elements >=
// approx 64th-largest-so-far; count(buf >= thr) >= 64 after; cnt >= 64.
__device__ __forceinline__ void wave_compact(float* s_buf, unsigned& cnt, float& thr, int lane) {
    __builtin_amdgcn_wave_barrier();
    unsigned key[NREG];
    load_keys(s_buf, cnt, lane, key);
    unsigned kmx = 0u;
    #pragma unroll
    for (int j = 0; j < NREG; ++j) kmx = max(kmx, key[j]);
    #pragma unroll
    for (int d = 1; d < 64; d <<= 1) kmx = max(kmx, (unsigned)__shfl_xor((int)kmx, d));

    unsigned lo = f2key(thr);   // invariant: count(key >= lo) >= 64
    unsigned hi = kmx + 1u;
    for (int it = 0; it < 12; ++it) {
        if (hi - lo <= 1u) break;
        const unsigned mid = lo + ((hi - lo) >> 1);
        int c = 0;
        #pragma unroll
        for (int j = 0; j < NREG; ++j) c += (key[j] >= mid) ? 1 : 0;
        c = wave_sum_i(c);
        if (c >= KTOP) lo = mid; else hi = mid;
    }
    int cl = 0; unsigned sm = 0u;
    #pragma unroll
    for (int j = 0; j < NREG; ++j) { const bool s = key[j] >= lo; sm |= (unsigned)s << j; cl += s ? 1 : 0; }
    int incl = cl;
    #pragma unroll
    for (int d = 1; d < 64; d <<= 1) { const int t = __shfl_up(incl, d); if (lane >= d) incl += t; }
    int pos = incl - cl;
    __builtin_amdgcn_wave_barrier();
    #pragma unroll
    for (int j = 0; j < NREG; ++j) if ((sm >> j) & 1u) s_buf[pos++] = key2f(key[j]);
    cnt = (unsigned)__shfl(incl, 63);
    thr = key2f(lo);
    __builtin_amdgcn_wave_barrier();
}

// Exact top-64 + label-smoothed CE over {truth, top64}. Tie-correct via
// boundary multiplicity. Runs once per row, after streaming.
__device__ __forceinline__ float wave_final(const float* s_buf, unsigned cnt, float thr, float tv, int lane) {
    __builtin_amdgcn_wave_barrier();
    unsigned key[NREG];
    load_keys(s_buf, cnt, lane, key);
    unsigned kmx = 0u;
    #pragma unroll
    for (int j = 0; j < NREG; ++j) kmx = max(kmx, key[j]);
    #pragma unroll
    for (int d = 1; d < 64; d <<= 1) kmx = max(kmx, (unsigned)__shfl_xor((int)kmx, d));

    unsigned lo = f2key(thr);
    unsigned hi = kmx + 1u;
    while (hi - lo > 1u) {
        const unsigned mid = lo + ((hi - lo) >> 1);
        int c = 0;
        #pragma unroll
        for (int j = 0; j < NREG; ++j) c += (key[j] >= mid) ? 1 : 0;
        c = wave_sum_i(c);
        if (c >= KTOP) lo = mid; else hi = mid;
    }
    const float vmax = key2f(kmx);
    const float m = fmaxf(vmax, tv);
    float se = 0.f, sv = 0.f; int cg = 0;
    #pragma unroll
    for (int j = 0; j < NREG; ++j) {
        if (key[j] > lo) { const float v = key2f(key[j]); se += __expf(v - m); sv += v; ++cg; }
    }
    #pragma unroll
    for (int d = 1; d < 64; d <<= 1) {
        se += __shfl_xor(se, d); sv += __shfl_xor(sv, d); cg += __shfl_xor(cg, d);
    }
    const float v64 = key2f(lo);            // exact 64th largest
    const int nb = KTOP - cg;               // boundary multiplicity (>=1)
    se += (float)nb * __expf(v64 - m);
    sv += (float)nb * v64;
    se += __expf(tv - m);
    const float lse = m + __logf(se);
    return lse - 0.9f * tv - 0.1f * ((sv + tv) * (1.0f / 65.0f));
}

// Ballot-aggregated wave insert; cnt is a wave-uniform register (no atomics).
__device__ __forceinline__ void ins1(float v, int gi, int tgt, float thr,
                                     float* s_buf, unsigned& cnt, unsigned long long lt) {
    const bool p = (v > thr) && (gi != tgt);
    const unsigned long long mk = __ballot(p ? 1 : 0);
    if (mk) {
        if (p) {
            const unsigned pos = cnt + (unsigned)__popcll(mk & lt);
            if (pos < CAP) s_buf[pos] = v;
        }
        cnt += (unsigned)__popcll(mk);
    }
}
__device__ __forceinline__ void ins4(const float4 q, int gb, int tgt, float thr,
                                     float* s_buf, unsigned& cnt, unsigned long long lt) {
    ins1(q.x, gb + 0, tgt, thr, s_buf, cnt, lt);
    ins1(q.y, gb + 1, tgt, thr, s_buf, cnt, lt);
    ins1(q.z, gb + 2, tgt, thr, s_buf, cnt, lt);
    ins1(q.w, gb + 3, tgt, thr, s_buf, cnt, lt);
}

// One wave (64-thread block) per row. 8-slot register ring: loads issued
// 8 tiles (32KB) ahead of consumption (source-level counted-vmcnt). All ring
// indices are compile-time constants after full unroll (rule #20), so the
// ring lives in VGPRs. No calls, no fences, no __syncthreads, no atomics.
__global__ __launch_bounds__(64) void topk_ce_kernel(
        const float* __restrict__ input, const int* __restrict__ target,
        float* __restrict__ per_ex, float* __restrict__ out_atomic) {
    __shared__ float s_buf[CAP];
    const int row  = blockIdx.x;
    const int lane = threadIdx.x;
    const float* __restrict__ rowp = input + (size_t)row * (size_t)VCOLS;
    const int tgt = target[row];
    const float tv = rowp[tgt];               // independent load, issued early
    const unsigned long long lt = (1ull << lane) - 1ull;

    unsigned cnt = 0u;
    float thr = -INFINITY;

    // Rows are only 4B-aligned (V % 4 == 1): scalar prologue to 16B boundary.
    const int pad = (int)((4u - ((((uintptr_t)rowp) >> 2) & 3u)) & 3u);
    {
        const float v = (lane < pad) ? rowp[lane] : 0.f;
        const bool p = (lane < pad) && (lane != tgt);
        const unsigned long long mk = __ballot(p ? 1 : 0);
        if (p) s_buf[cnt + __popcll(mk & lt)] = v;
        cnt += (unsigned)__popcll(mk);
    }

    const int nvec  = (VCOLS - pad) >> 2;
    const int ntail = (VCOLS - pad) & 3;
    const float4* __restrict__ vp = (const float4*)(rowp + pad);
    const int ntf = nvec >> 8;   // full tiles: 256 quads = 1024 elems (=49)

    // 8-slot ring, tiles 0..7 in flight before any processing
    float4 ring[8][4];
    #pragma unroll
    for (int s = 0; s < 8; ++s) {
        if (s < ntf) {
            const int b = s * 256 + lane;
            ring[s][0] = vp[b];
            ring[s][1] = vp[b + 64];
            ring[s][2] = vp[b + 128];
            ring[s][3] = vp[b + 192];
        }
    }

    for (int t = 0; t < ntf; t += 8) {
        #pragma unroll
        for (int s = 0; s < 8; ++s) {
            const int tq = t + s;
            if (tq < ntf) {                  // wave-uniform guard
                const int bq = tq * 256 + lane;
                const float4 q0 = ring[s][0];
                const float4 q1 = ring[s][1];
                const float4 q2 = ring[s][2];
                const float4 q3 = ring[s][3];
                // refill slot s with tile tq+8 (issued before the compare path)
                if (tq + 8 < ntf) {
                    const int bn = (tq + 8) * 256 + lane;
                    ring[s][0] = vp[bn];
                    ring[s][1] = vp[bn + 64];
                    ring[s][2] = vp[bn + 128];
                    ring[s][3] = vp[bn + 192];
                }
                const float m0 = fmaxf(fmaxf(q0.x, q0.y), fmaxf(q0.z, q0.w));
                const float m1 = fmaxf(fmaxf(q1.x, q1.y), fmaxf(q1.z, q1.w));
                const float m2 = fmaxf(fmaxf(q2.x, q2.y), fmaxf(q2.z, q2.w));
                const float m3 = fmaxf(fmaxf(q3.x, q3.y), fmaxf(q3.z, q3.w));
                const float m16 = fmaxf(fmaxf(m0, m1), fmaxf(m2, m3));
                if (__ballot((m16 > thr) ? 1 : 0)) {
                    ins4(q0, pad + 4 * bq,         tgt, thr, s_buf, cnt, lt);
                    ins4(q1, pad + 4 * (bq + 64),  tgt, thr, s_buf, cnt, lt);
                    ins4(q2, pad + 4 * (bq + 128), tgt, thr, s_buf, cnt, lt);
                    ins4(q3, pad + 4 * (bq + 192), tgt, thr, s_buf, cnt, lt);
                }
                if (cnt > CHECK_AT) wave_compact(s_buf, cnt, thr, lane);
            }
        }
    }

    // masked remainder quads (< 256), uniform trip count
    for (int k0 = ntf << 8; k0 < nvec; k0 += 64) {
        const int idx = k0 + lane;
        float4 a;
        if (idx < nvec) a = vp[idx];
        else { a.x = a.y = a.z = a.w = -INFINITY; }
        const float mA = fmaxf(fmaxf(a.x, a.y), fmaxf(a.z, a.w));
        if (__ballot((mA > thr) ? 1 : 0)) ins4(a, pad + 4 * idx, tgt, thr, s_buf, cnt, lt);
        if (cnt > CHECK_AT) wave_compact(s_buf, cnt, thr, lane);
    }

    // scalar tail (<= 3 elems)
    {
        const int idx = pad + 4 * nvec + lane;
        const float v = (lane < ntail) ? rowp[idx] : 0.f;
        const bool p = (lane < ntail) && (v > thr) && (idx != tgt);
        const unsigned long long mk = __ballot(p ? 1 : 0);
        if (p) {
            const unsigned pos = cnt + (unsigned)__popcll(mk & lt);
            if (pos < CAP) s_buf[pos] = v;
        }
        cnt += (unsigned)__popcll(mk);
    }

    const float pe = wave_final(s_buf, cnt, thr, tv, lane);
    if (lane == 0) {
        if (per_ex) per_ex[row] = pe;
        else atomicAdd(out_atomic, pe * (1.0f / BROWS));
    }
}

// Deterministic mean of the 4096 per-row losses (float4 loads).
__global__ __launch_bounds__(256) void reduce_mean_kernel(
        const float* __restrict__ per_ex, float* __restrict__ out) {
    __shared__ float s[256];
    const int tid = threadIdx.x;
    const float4* p4 = (const float4*)per_ex;
    float acc = 0.0f;
    #pragma unroll
    for (int i = 0; i < BROWS / 1024; ++i) {   // 4 float4 per thread
        const float4 v = p4[i * 256 + tid];
        acc += (v.x + v.y) + (v.z + v.w);
    }
    s[tid] = acc;
    __syncthreads();
    for (int w = 128; w > 0; w >>= 1) {
        if (tid < w) s[tid] += s[tid + w];
        __syncthreads();
    }
    if (tid == 0) out[0] = s[0] * (1.0f / BROWS);
}

extern "C" void kernel_launch(void* const* d_in, const int* in_sizes, int n_in,
                              void* d_out, int out_size, void* d_ws, size_t ws_size,
                              hipStream_t stream) {
    const float* input  = (const float*)d_in[0];
    const int*   target = (const int*)d_in[1];   // jax int64 -> int32 on device (x64 off)
    float* out = (float*)d_out;

    if (ws_size >= BROWS * sizeof(float)) {
        float* per_ex = (float*)d_ws;
        topk_ce_kernel<<<BROWS, 64, 0, stream>>>(input, target, per_ex, nullptr);
        reduce_mean_kernel<<<1, 256, 0, stream>>>(per_ex, out);
    } else {
        hipMemsetAsync(d_out, 0, sizeof(float), stream);
        topk_ce_kernel<<<BROWS, 64, 0, stream>>>(input, target, nullptr, out);
    }
}